// Round 1
// baseline (21972.601 us; speedup 1.0000x reference)
//
#include <hip/hip_runtime.h>
#include <math.h>

#define SS 512
#define BB 64
#define II 512
#define HH 1024

// Per-step kernel: grid = 256 blocks, block j owns h-indices [4j, 4j+4) x 4 gates
// x all 64 batches. 256 threads: thread (r = t>>4, bq = t&15) accumulates
// 4 batch outputs for one (gate,h) row. K = 1024 (h_prev) + 512 (x[s]) fused.

struct LstmParams {
  const float* x;     // [S,B,I]
  const float* h0;    // [B,H]
  const float* c0;    // [B,H]
  const float* Wh[4]; // each [H,H], gate order f,i,o,c
  const float* Wx[4]; // each [H,I]
  const float* bx[4]; // [H]
  const float* bh[4]; // [H]
  float* out;         // [S*B*H + 2*B*H]
  float* cws;         // [B,H] scratch cell state
};

__global__ __launch_bounds__(256) void lstm_step(LstmParams p, int s) {
  __shared__ float hl[64][68];  // k-major src tile: hl[kk][b], pad->conflict-free
  __shared__ float wl[16][68];  // w tile: wl[row][kk]
  __shared__ float gl[16][66];  // gate exchange

  const int t  = threadIdx.x;
  const int hb = blockIdx.x * 4;
  const int rr = t >> 4;        // 0..15: row within block (g = rr>>2, hsub = rr&3)
  const int bq = t & 15;        // batch quad
  const int g  = rr >> 2;
  const int hrow = hb + (rr & 3);

  const float* hsrc = (s == 0) ? p.h0 : (p.out + (size_t)(s - 1) * BB * HH);
  const float* csrc = (s == 0) ? p.c0 : p.cws;

  float acc0 = 0.f, acc1 = 0.f, acc2 = 0.f, acc3 = 0.f;

  // staging registers (global -> reg -> LDS pipeline)
  float4 wv, hv0, hv1, hv2, hv3;

  const int c4 = (t & 15) * 4;  // col within 64-wide chunk for loads
  const int bb = t >> 4;        // base batch row for src loads

  auto issue_loads = [&](int ch) {
    const float* wbase; const float* sbase; int sstride, Kw, k0;
    if (ch < 16) { k0 = ch * 64;        wbase = p.Wh[g]; sbase = hsrc;                     sstride = HH; Kw = HH; }
    else         { k0 = (ch - 16) * 64; wbase = p.Wx[g]; sbase = p.x + (size_t)s * BB * II; sstride = II; Kw = II; }
    wv  = *(const float4*)(wbase + (size_t)hrow * Kw + k0 + c4);
    hv0 = *(const float4*)(sbase + (size_t)(bb +  0) * sstride + k0 + c4);
    hv1 = *(const float4*)(sbase + (size_t)(bb + 16) * sstride + k0 + c4);
    hv2 = *(const float4*)(sbase + (size_t)(bb + 32) * sstride + k0 + c4);
    hv3 = *(const float4*)(sbase + (size_t)(bb + 48) * sstride + k0 + c4);
  };

  auto store_stage = [&]() {
    *(float4*)&wl[rr][c4] = wv;
    hl[c4 + 0][bb +  0] = hv0.x; hl[c4 + 1][bb +  0] = hv0.y;
    hl[c4 + 2][bb +  0] = hv0.z; hl[c4 + 3][bb +  0] = hv0.w;
    hl[c4 + 0][bb + 16] = hv1.x; hl[c4 + 1][bb + 16] = hv1.y;
    hl[c4 + 2][bb + 16] = hv1.z; hl[c4 + 3][bb + 16] = hv1.w;
    hl[c4 + 0][bb + 32] = hv2.x; hl[c4 + 1][bb + 32] = hv2.y;
    hl[c4 + 2][bb + 32] = hv2.z; hl[c4 + 3][bb + 32] = hv2.w;
    hl[c4 + 0][bb + 48] = hv3.x; hl[c4 + 1][bb + 48] = hv3.y;
    hl[c4 + 2][bb + 48] = hv3.z; hl[c4 + 3][bb + 48] = hv3.w;
  };

  auto compute_chunk = [&]() {
#pragma unroll
    for (int kk4 = 0; kk4 < 64; kk4 += 4) {
      float4 w4 = *(const float4*)&wl[rr][kk4];
      float4 hq;
      hq = *(const float4*)&hl[kk4 + 0][bq * 4];
      acc0 += w4.x * hq.x; acc1 += w4.x * hq.y; acc2 += w4.x * hq.z; acc3 += w4.x * hq.w;
      hq = *(const float4*)&hl[kk4 + 1][bq * 4];
      acc0 += w4.y * hq.x; acc1 += w4.y * hq.y; acc2 += w4.y * hq.z; acc3 += w4.y * hq.w;
      hq = *(const float4*)&hl[kk4 + 2][bq * 4];
      acc0 += w4.z * hq.x; acc1 += w4.z * hq.y; acc2 += w4.z * hq.z; acc3 += w4.z * hq.w;
      hq = *(const float4*)&hl[kk4 + 3][bq * 4];
      acc0 += w4.w * hq.x; acc1 += w4.w * hq.y; acc2 += w4.w * hq.z; acc3 += w4.w * hq.w;
    }
  };

  // prologue: stage chunk 0
  issue_loads(0);
  store_stage();
  __syncthreads();

  for (int ch = 0; ch < 24; ++ch) {
    const bool more = (ch + 1 < 24);
    if (more) issue_loads(ch + 1);  // global loads in flight during compute
    compute_chunk();
    __syncthreads();                // everyone done reading LDS
    if (more) store_stage();        // s_waitcnt vmcnt happens here
    __syncthreads();                // LDS ready for next chunk
  }

  // exchange gate pre-activations: gl[row][b]
  gl[rr][bq * 4 + 0] = acc0;
  gl[rr][bq * 4 + 1] = acc1;
  gl[rr][bq * 4 + 2] = acc2;
  gl[rr][bq * 4 + 3] = acc3;
  __syncthreads();

  // epilogue: thread (hsub = t&3, b = t>>2) combines 4 gates for one (b,h)
  const int hsub = t & 3;
  const int b    = t >> 2;
  const int hg   = hb + hsub;

  float pf = gl[ 0 + hsub][b] + p.bx[0][hg] + p.bh[0][hg];
  float pi = gl[ 4 + hsub][b] + p.bx[1][hg] + p.bh[1][hg];
  float po = gl[ 8 + hsub][b] + p.bx[2][hg] + p.bh[2][hg];
  float pc = gl[12 + hsub][b] + p.bx[3][hg] + p.bh[3][hg];

  float fg = 1.f / (1.f + expf(-pf));
  float ig = 1.f / (1.f + expf(-pi));
  float og = 1.f / (1.f + expf(-po));
  float cg = tanhf(pc);

  float cp = csrc[(size_t)b * HH + hg];
  float cn = fg * cp + ig * cg;
  float hn = og * tanhf(cn);

  p.out[(size_t)s * BB * HH + (size_t)b * HH + hg] = hn;
  p.cws[(size_t)b * HH + hg] = cn;
  if (s == SS - 1) {
    p.out[(size_t)SS * BB * HH + (size_t)b * HH + hg] = hn;            // h_last
    p.out[(size_t)SS * BB * HH + BB * HH + (size_t)b * HH + hg] = cn;  // c_last
  }
}

extern "C" void kernel_launch(void* const* d_in, const int* in_sizes, int n_in,
                              void* d_out, int out_size, void* d_ws, size_t ws_size,
                              hipStream_t stream) {
  (void)in_sizes; (void)n_in; (void)out_size; (void)ws_size;
  LstmParams p;
  p.x  = (const float*)d_in[0];
  p.h0 = (const float*)d_in[1];
  p.c0 = (const float*)d_in[2];
  // dict order: Wfx,bfx,Wfh,bfh, Wix,bix,Wih,bih, Wox,b_ox,Woh,boh, Wcx,bcx,Wch,bch
  p.Wx[0] = (const float*)d_in[3];  p.bx[0] = (const float*)d_in[4];
  p.Wh[0] = (const float*)d_in[5];  p.bh[0] = (const float*)d_in[6];
  p.Wx[1] = (const float*)d_in[7];  p.bx[1] = (const float*)d_in[8];
  p.Wh[1] = (const float*)d_in[9];  p.bh[1] = (const float*)d_in[10];
  p.Wx[2] = (const float*)d_in[11]; p.bx[2] = (const float*)d_in[12];
  p.Wh[2] = (const float*)d_in[13]; p.bh[2] = (const float*)d_in[14];
  p.Wx[3] = (const float*)d_in[15]; p.bx[3] = (const float*)d_in[16];
  p.Wh[3] = (const float*)d_in[17]; p.bh[3] = (const float*)d_in[18];
  p.out = (float*)d_out;
  p.cws = (float*)d_ws;  // 256 KB cell-state scratch

  for (int s = 0; s < SS; ++s) {
    lstm_step<<<dim3(256), dim3(256), 0, stream>>>(p, s);
  }
}

// Round 5
// 7330.297 us; speedup vs baseline: 2.9975x; 2.9975x over previous
//
#include <hip/hip_runtime.h>
#include <math.h>

#define SS 512
#define BB 64
#define II 512
#define HH 1024

typedef __attribute__((ext_vector_type(8))) __bf16 bf16x8;
typedef __attribute__((ext_vector_type(4))) float f32x4;

// ---------------- ws layout (bf16-element offsets) ----------------
// wpack : 256 wg * 48 iters * 64 lanes * 8 bf16 = 6,291,456 elems (12.58 MB)
// hbf0/1: 2 * 65536 bf16
// cbuf  : 65536 fp32
#define WPACK_ELEMS (256u * 48u * 64u * 8u)
#define HBF_ELEMS   (BB * HH)

struct StepParams {
  const float* x;        // [S,B,I] fp32
  const __bf16* wpack;   // packed weights
  const __bf16* hbf_in;  // [B,H] bf16
  __bf16* hbf_out;       // [B,H] bf16
  float* cbuf;           // [B,H] fp32
  const float* bx[4];    // biases (f,i,o,c)
  const float* bh[4];
  float* out;            // [S*B*H + 2*B*H] fp32
};

// wg wb owns h-indices [4*wb, 4*wb+4) x 4 gates (16 M-rows) x 64 batches.
// wave w handles batches [16w,16w+16). 48 MFMA iters: 32 over h (K=1024),
// 16 over x (K=512, fp32->bf16 on the fly).
__global__ __launch_bounds__(256) void lstm_step_mfma(StepParams p, int s) {
  const int wb = blockIdx.x;
  const int hb = wb * 4;
  const int t = threadIdx.x;
  const int w = t >> 6;
  const int lane = t & 63;

  const int kof  = (lane >> 4) * 8;       // k-offset within 32-chunk
  const int bcol = w * 16 + (lane & 15);  // batch column

  // A: packed weights, lane-linear 16B chunks -> perfectly coalesced stream
  const __bf16* ap = p.wpack + (((size_t)wb * 48) * 64 + lane) * 8;
  // B: z = concat(h_prev bf16, x[s] fp32)
  const __bf16* bhp = p.hbf_in + (size_t)bcol * HH + kof;
  const float*  bxp = p.x + ((size_t)s * BB + bcol) * II + kof;

  f32x4 acc = {0.f, 0.f, 0.f, 0.f};

#pragma unroll 8
  for (int it = 0; it < 32; ++it) {
    bf16x8 a = *(const bf16x8*)(ap + (size_t)it * 512);
    bf16x8 b = *(const bf16x8*)(bhp + it * 32);
    acc = __builtin_amdgcn_mfma_f32_16x16x32_bf16(a, b, acc, 0, 0, 0);
  }
  const __bf16* ap2 = ap + 32 * 512;
#pragma unroll 4
  for (int it = 0; it < 16; ++it) {
    bf16x8 a = *(const bf16x8*)(ap2 + (size_t)it * 512);
    const float* xp = bxp + it * 32;
    float4 x0 = *(const float4*)(xp);
    float4 x1 = *(const float4*)(xp + 4);
    bf16x8 b;
    b[0] = (__bf16)x0.x; b[1] = (__bf16)x0.y; b[2] = (__bf16)x0.z; b[3] = (__bf16)x0.w;
    b[4] = (__bf16)x1.x; b[5] = (__bf16)x1.y; b[6] = (__bf16)x1.z; b[7] = (__bf16)x1.w;
    acc = __builtin_amdgcn_mfma_f32_16x16x32_bf16(a, b, acc, 0, 0, 0);
  }

  // D tile: col = lane&15 (batch), row = (lane>>4)*4 + r (m-row: 4*gate+hsub)
  __shared__ float gl[4][16][17];
  const int drow = (lane >> 4) * 4;
  gl[w][drow + 0][lane & 15] = acc[0];
  gl[w][drow + 1][lane & 15] = acc[1];
  gl[w][drow + 2][lane & 15] = acc[2];
  gl[w][drow + 3][lane & 15] = acc[3];
  __syncthreads();

  // epilogue: thread -> (batch b, hsub)
  const int b    = t >> 2;
  const int hsub = t & 3;
  const int hg   = hb + hsub;
  const int wq   = b >> 4;
  const int bc   = b & 15;

  float pf = gl[wq][ 0 + hsub][bc] + p.bx[0][hg] + p.bh[0][hg];
  float pi = gl[wq][ 4 + hsub][bc] + p.bx[1][hg] + p.bh[1][hg];
  float po = gl[wq][ 8 + hsub][bc] + p.bx[2][hg] + p.bh[2][hg];
  float pc = gl[wq][12 + hsub][bc] + p.bx[3][hg] + p.bh[3][hg];

  float fg = 1.f / (1.f + __expf(-pf));
  float ig = 1.f / (1.f + __expf(-pi));
  float og = 1.f / (1.f + __expf(-po));
  float cg = tanhf(pc);

  const size_t ci = (size_t)b * HH + hg;
  float cp = p.cbuf[ci];
  float cn = fg * cp + ig * cg;
  float hn = og * tanhf(cn);

  p.out[(size_t)s * BB * HH + ci] = hn;
  p.hbf_out[ci] = (__bf16)hn;
  p.cbuf[ci] = cn;
  if (s == SS - 1) {
    p.out[(size_t)SS * BB * HH + ci] = hn;             // h_last
    p.out[(size_t)SS * BB * HH + BB * HH + ci] = cn;   // c_last
  }
}

struct PackParams {
  const float* Wh[4];
  const float* Wx[4];
  __bf16* wpack;
};

// Pack fp32 weights into per-(wg,iter,lane) bf16x8 fragments.
__global__ __launch_bounds__(256) void pack_weights(PackParams p) {
  const int wb = blockIdx.x;
  const int t = threadIdx.x;
  const int it2 = t >> 6;
  const int lane = t & 63;
  const int r16 = lane & 15;
  const int g = r16 >> 2;
  const int hrow = wb * 4 + (r16 & 3);
  const int kof = (lane >> 4) * 8;
  for (int itb = 0; itb < 12; ++itb) {
    const int it = itb * 4 + it2;
    const float* src;
    if (it < 32) src = p.Wh[g] + (size_t)hrow * HH + it * 32 + kof;
    else         src = p.Wx[g] + (size_t)hrow * II + (it - 32) * 32 + kof;
    float4 s0 = *(const float4*)(src);
    float4 s1 = *(const float4*)(src + 4);
    bf16x8 v;
    v[0] = (__bf16)s0.x; v[1] = (__bf16)s0.y; v[2] = (__bf16)s0.z; v[3] = (__bf16)s0.w;
    v[4] = (__bf16)s1.x; v[5] = (__bf16)s1.y; v[6] = (__bf16)s1.z; v[7] = (__bf16)s1.w;
    *(bf16x8*)(p.wpack + (((size_t)wb * 48 + it) * 64 + lane) * 8) = v;
  }
}

__global__ __launch_bounds__(256) void prep_state(const float* h0, const float* c0,
                                                  __bf16* hbf0, float* cbuf) {
  const int i = blockIdx.x * 256 + threadIdx.x;  // grid 256 -> 65536
  hbf0[i] = (__bf16)h0[i];
  cbuf[i] = c0[i];
}

extern "C" void kernel_launch(void* const* d_in, const int* in_sizes, int n_in,
                              void* d_out, int out_size, void* d_ws, size_t ws_size,
                              hipStream_t stream) {
  (void)in_sizes; (void)n_in; (void)out_size; (void)ws_size;

  __bf16* wsb = (__bf16*)d_ws;
  __bf16* wpack = wsb;
  __bf16* hbf0 = wsb + WPACK_ELEMS;
  __bf16* hbf1 = hbf0 + HBF_ELEMS;
  float*  cbuf = (float*)(wsb + WPACK_ELEMS + 2 * HBF_ELEMS);

  // dict order: x,h,c, Wfx,bfx,Wfh,bfh, Wix,bix,Wih,bih, Wox,b_ox,Woh,boh, Wcx,bcx,Wch,bch
  PackParams pk;
  pk.Wx[0] = (const float*)d_in[3];  pk.Wh[0] = (const float*)d_in[5];
  pk.Wx[1] = (const float*)d_in[7];  pk.Wh[1] = (const float*)d_in[9];
  pk.Wx[2] = (const float*)d_in[11]; pk.Wh[2] = (const float*)d_in[13];
  pk.Wx[3] = (const float*)d_in[15]; pk.Wh[3] = (const float*)d_in[17];
  pk.wpack = wpack;

  StepParams p;
  p.x = (const float*)d_in[0];
  p.wpack = wpack;
  p.cbuf = cbuf;
  p.bx[0] = (const float*)d_in[4];  p.bh[0] = (const float*)d_in[6];
  p.bx[1] = (const float*)d_in[8];  p.bh[1] = (const float*)d_in[10];
  p.bx[2] = (const float*)d_in[12]; p.bh[2] = (const float*)d_in[14];
  p.bx[3] = (const float*)d_in[16]; p.bh[3] = (const float*)d_in[18];
  p.out = (float*)d_out;

  pack_weights<<<dim3(256), dim3(256), 0, stream>>>(pk);
  prep_state<<<dim3(256), dim3(256), 0, stream>>>(
      (const float*)d_in[1], (const float*)d_in[2], hbf0, cbuf);

  for (int s = 0; s < SS; ++s) {
    p.hbf_in  = (s & 1) ? hbf1 : hbf0;
    p.hbf_out = (s & 1) ? hbf0 : hbf1;
    lstm_step_mfma<<<dim3(256), dim3(256), 0, stream>>>(p, s);
  }
}

// Round 9
// 6492.537 us; speedup vs baseline: 3.3843x; 1.1290x over previous
//
#include <hip/hip_runtime.h>
#include <math.h>

#define SS 512
#define BB 64
#define II 512
#define HH 1024

typedef __attribute__((ext_vector_type(8))) __bf16 bf16x8;
typedef __attribute__((ext_vector_type(4))) float f32x4;

// ---------------- ws layout (bf16-element offsets) ----------------
// wpack : 256 wg * 48 iters * 64 lanes * 8 bf16 = 6,291,456 elems (12.58 MB)
// hbf0/1: 2 * 65536 bf16
// cbuf  : 65536 fp32
#define WPACK_ELEMS (256u * 48u * 64u * 8u)
#define HBF_ELEMS   (BB * HH)

struct StepParams {
  const float* x;        // [S,B,I] fp32
  const __bf16* wpack;   // packed weights
  const __bf16* hbf_in;  // [B,H] bf16
  __bf16* hbf_out;       // [B,H] bf16
  float* cbuf;           // [B,H] fp32
  const float* bx[4];    // biases (f,i,o,c)
  const float* bh[4];
  float* out;            // [S*B*H + 2*B*H] fp32
};

// wg wb owns h-indices [4*wb, 4*wb+4) x 4 gates (16 M-rows) x 64 batches.
// 16 waves: wave w = (ks = w>>2, bg = w&3). bg picks batches [16bg,16bg+16);
// ks picks K-slice: h-iters {ks,ks+4,...,ks+28} (8) + x-iters {32+ks,...} (4).
// Split-K x4 -> 16 waves/CU (4/SIMD) for latency hiding; LDS reduce.
__global__ __launch_bounds__(1024) void lstm_step_mfma(StepParams p, int s) {
  __shared__ float part[4][4][16][17];  // [ks][bg][row][col]
  __shared__ float pre[4][16][17];      // [bg][row][col] reduced pre-activations

  const int wb = blockIdx.x;
  const int t = threadIdx.x;
  const int w = t >> 6;
  const int lane = t & 63;
  const int bg = w & 3;
  const int ks = w >> 2;

  const int kof  = (lane >> 4) * 8;        // k-offset within 32-chunk
  const int bcol = bg * 16 + (lane & 15);  // batch column

  const __bf16* ap  = p.wpack + (((size_t)wb * 48) * 64 + lane) * 8;
  const __bf16* bhp = p.hbf_in + (size_t)bcol * HH + kof;
  const float*  bxp = p.x + ((size_t)s * BB + bcol) * II + kof;

  f32x4 acc = {0.f, 0.f, 0.f, 0.f};

#pragma unroll
  for (int j = 0; j < 8; ++j) {
    const int it = ks + 4 * j;
    bf16x8 a = *(const bf16x8*)(ap + (size_t)it * 512);
    bf16x8 b = *(const bf16x8*)(bhp + it * 32);
    acc = __builtin_amdgcn_mfma_f32_16x16x32_bf16(a, b, acc, 0, 0, 0);
  }
#pragma unroll
  for (int j = 0; j < 4; ++j) {
    const int it = 32 + ks + 4 * j;
    bf16x8 a = *(const bf16x8*)(ap + (size_t)it * 512);
    const float* xp = bxp + (it - 32) * 32;
    float4 x0 = *(const float4*)(xp);
    float4 x1 = *(const float4*)(xp + 4);
    bf16x8 b;
    b[0] = (__bf16)x0.x; b[1] = (__bf16)x0.y; b[2] = (__bf16)x0.z; b[3] = (__bf16)x0.w;
    b[4] = (__bf16)x1.x; b[5] = (__bf16)x1.y; b[6] = (__bf16)x1.z; b[7] = (__bf16)x1.w;
    acc = __builtin_amdgcn_mfma_f32_16x16x32_bf16(a, b, acc, 0, 0, 0);
  }

  // D tile: col = lane&15 (batch), row = (lane>>4)*4 + r
  const int drow = (lane >> 4) * 4;
  part[ks][bg][drow + 0][lane & 15] = acc[0];
  part[ks][bg][drow + 1][lane & 15] = acc[1];
  part[ks][bg][drow + 2][lane & 15] = acc[2];
  part[ks][bg][drow + 3][lane & 15] = acc[3];
  __syncthreads();

  // reduce 4 K-slices: 1024 threads cover [bg][row][col]
  {
    const int rbg = t >> 8;
    const int row = (t >> 4) & 15;
    const int bc  = t & 15;
    pre[rbg][row][bc] = part[0][rbg][row][bc] + part[1][rbg][row][bc]
                      + part[2][rbg][row][bc] + part[3][rbg][row][bc];
  }
  __syncthreads();

  // epilogue: thread t<256 -> (batch b, hsub)
  if (t < 256) {
    const int b    = t >> 2;
    const int hsub = t & 3;
    const int hg   = wb * 4 + hsub;
    const int bg2  = b >> 4;
    const int bc   = b & 15;

    float pf = pre[bg2][ 0 + hsub][bc] + p.bx[0][hg] + p.bh[0][hg];
    float pi = pre[bg2][ 4 + hsub][bc] + p.bx[1][hg] + p.bh[1][hg];
    float po = pre[bg2][ 8 + hsub][bc] + p.bx[2][hg] + p.bh[2][hg];
    float pc = pre[bg2][12 + hsub][bc] + p.bx[3][hg] + p.bh[3][hg];

    float fg = 1.f / (1.f + __expf(-pf));
    float ig = 1.f / (1.f + __expf(-pi));
    float og = 1.f / (1.f + __expf(-po));
    float cg = tanhf(pc);

    const size_t ci = (size_t)b * HH + hg;
    float cp = p.cbuf[ci];
    float cn = fg * cp + ig * cg;
    float hn = og * tanhf(cn);

    p.out[(size_t)s * BB * HH + ci] = hn;
    p.hbf_out[ci] = (__bf16)hn;
    p.cbuf[ci] = cn;
    if (s == SS - 1) {
      p.out[(size_t)SS * BB * HH + ci] = hn;             // h_last
      p.out[(size_t)SS * BB * HH + BB * HH + ci] = cn;   // c_last
    }
  }
}

struct PackParams {
  const float* Wh[4];
  const float* Wx[4];
  __bf16* wpack;
};

// Pack fp32 weights into per-(wg,iter,lane) bf16x8 fragments.
__global__ __launch_bounds__(256) void pack_weights(PackParams p) {
  const int wb = blockIdx.x;
  const int t = threadIdx.x;
  const int it2 = t >> 6;
  const int lane = t & 63;
  const int r16 = lane & 15;
  const int g = r16 >> 2;
  const int hrow = wb * 4 + (r16 & 3);
  const int kof = (lane >> 4) * 8;
  for (int itb = 0; itb < 12; ++itb) {
    const int it = itb * 4 + it2;
    const float* src;
    if (it < 32) src = p.Wh[g] + (size_t)hrow * HH + it * 32 + kof;
    else         src = p.Wx[g] + (size_t)hrow * II + (it - 32) * 32 + kof;
    float4 s0 = *(const float4*)(src);
    float4 s1 = *(const float4*)(src + 4);
    bf16x8 v;
    v[0] = (__bf16)s0.x; v[1] = (__bf16)s0.y; v[2] = (__bf16)s0.z; v[3] = (__bf16)s0.w;
    v[4] = (__bf16)s1.x; v[5] = (__bf16)s1.y; v[6] = (__bf16)s1.z; v[7] = (__bf16)s1.w;
    *(bf16x8*)(p.wpack + (((size_t)wb * 48 + it) * 64 + lane) * 8) = v;
  }
}

__global__ __launch_bounds__(256) void prep_state(const float* h0, const float* c0,
                                                  __bf16* hbf0, float* cbuf) {
  const int i = blockIdx.x * 256 + threadIdx.x;  // grid 256 -> 65536
  hbf0[i] = (__bf16)h0[i];
  cbuf[i] = c0[i];
}

extern "C" void kernel_launch(void* const* d_in, const int* in_sizes, int n_in,
                              void* d_out, int out_size, void* d_ws, size_t ws_size,
                              hipStream_t stream) {
  (void)in_sizes; (void)n_in; (void)out_size; (void)ws_size;

  __bf16* wsb = (__bf16*)d_ws;
  __bf16* wpack = wsb;
  __bf16* hbf0 = wsb + WPACK_ELEMS;
  __bf16* hbf1 = hbf0 + HBF_ELEMS;
  float*  cbuf = (float*)(wsb + WPACK_ELEMS + 2 * HBF_ELEMS);

  // dict order: x,h,c, Wfx,bfx,Wfh,bfh, Wix,bix,Wih,bih, Wox,b_ox,Woh,boh, Wcx,bcx,Wch,bch
  PackParams pk;
  pk.Wx[0] = (const float*)d_in[3];  pk.Wh[0] = (const float*)d_in[5];
  pk.Wx[1] = (const float*)d_in[7];  pk.Wh[1] = (const float*)d_in[9];
  pk.Wx[2] = (const float*)d_in[11]; pk.Wh[2] = (const float*)d_in[13];
  pk.Wx[3] = (const float*)d_in[15]; pk.Wh[3] = (const float*)d_in[17];
  pk.wpack = wpack;

  StepParams p;
  p.x = (const float*)d_in[0];
  p.wpack = wpack;
  p.cbuf = cbuf;
  p.bx[0] = (const float*)d_in[4];  p.bh[0] = (const float*)d_in[6];
  p.bx[1] = (const float*)d_in[8];  p.bh[1] = (const float*)d_in[10];
  p.bx[2] = (const float*)d_in[12]; p.bh[2] = (const float*)d_in[14];
  p.bx[3] = (const float*)d_in[16]; p.bh[3] = (const float*)d_in[18];
  p.out = (float*)d_out;

  pack_weights<<<dim3(256), dim3(256), 0, stream>>>(pk);
  prep_state<<<dim3(256), dim3(256), 0, stream>>>(
      (const float*)d_in[1], (const float*)d_in[2], hbf0, cbuf);

  for (int s = 0; s < SS; ++s) {
    p.hbf_in  = (s & 1) ? hbf1 : hbf0;
    p.hbf_out = (s & 1) ? hbf0 : hbf1;
    lstm_step_mfma<<<dim3(256), dim3(1024), 0, stream>>>(p, s);
  }
}